// Round 1
// 619.458 us; speedup vs baseline: 1.0154x; 1.0154x over previous
//
#include <hip/hip_runtime.h>

// NeighborAttention fused, round 3: multi-tile persistent pipeline.
// 4 tiles (8 tokens) per block, two register staging batches so global loads
// are always in flight; Q/O projections hoisted to once-per-block with 4-way
// ILP. B=4,N=2000,K=30,H=128,HEADS=4,D=32,NUM_IN=256. fp32 in/out, bf16 MFMA.

#define KNB 30
#define HH 128
#define NUMIN 256
#define TOK 8000
#define TOTROW (TOK*KNB)    // 240000
#define TILES 4             // tiles per block, 2 tokens each
#define TOKB (2*TILES)      // 8 tokens per block
#define NBLK (TOK/TOKB)     // 1000
#define SAW 136             // LDS row stride (bf16 elems): 128 + 8 pad

typedef __bf16 bf16x8 __attribute__((ext_vector_type(8)));
typedef __bf16 bf16x4_t __attribute__((ext_vector_type(4)));
typedef float f32x4 __attribute__((ext_vector_type(4)));

// ws layout (bf16): [W_K1 16384][W_K2 16384][W_V 32768]
__global__ __launch_bounds__(256) void conv_w_kernel(
    const float* __restrict__ wk1, const float* __restrict__ wk2,
    const float* __restrict__ wv, __bf16* __restrict__ ws) {
  int e = (blockIdx.x * 256 + threadIdx.x) * 4;
  const float* src; int off;
  if (e < 16384)      { src = wk1; off = e; }
  else if (e < 32768) { src = wk2; off = e - 16384; }
  else                { src = wv;  off = e - 32768; }
  float4 v = *(const float4*)(src + off);
  bf16x4_t o4;
  o4.x = (__bf16)v.x; o4.y = (__bf16)v.y; o4.z = (__bf16)v.z; o4.w = (__bf16)v.w;
  *(bf16x4_t*)(ws + e) = o4;
}

__global__ __launch_bounds__(256, 3) void na_main_kernel(
    const float* __restrict__ h_V, const float* __restrict__ h_EV,
    const float* __restrict__ h_KV, const float* __restrict__ h_KE,
    const float* __restrict__ maskp, const float* __restrict__ W_Q,
    const float* __restrict__ W_O, const __bf16* __restrict__ bW,
    float* __restrict__ out) {
  __shared__ __bf16 sA[2][64 * SAW];   // double-buffered staging, 2x17408 B
  __shared__ float sQ[TOKB][HH];       // 4 KB
  __shared__ float sU[TOKB][HH];       // 4 KB
  __shared__ float sMask[TOKB][32];    // 1 KB

  const int tid = threadIdx.x;
  const int lane = tid & 63;
  const int wave = tid >> 6;           // wave == head
  const int m = lane & 15;
  const int quad = lane >> 4;
  const int tok0 = blockIdx.x * TOKB;

  const __bf16* bWK1 = bW;
  const __bf16* bWK2 = bW + 16384;
  const __bf16* bWV  = bW + 32768;

  // ---- staging: 64 rows x 128 cols fp32 -> bf16 LDS; 8 float4 per thread ----
  const int srow = tid >> 5;           // 0..7
  const int scol = (tid & 31) << 2;    // 0..124

  float4 svA[8], svB[8];               // two in-flight batches

  auto stage_load = [&](float4 (&sv)[8], const float* base, int ld, int tile,
                        int coloff) {
    const long r0 = (long)(tok0 + 2 * tile) * KNB + srow;
#pragma unroll
    for (int j = 0; j < 8; j++) {
      long rr = r0 + j * 8;
      if (rr > TOTROW - 1) rr = TOTROW - 1;   // clamp (array end only)
      sv[j] = *(const float4*)(base + rr * (long)ld + coloff + scol);
    }
  };
  auto stage_store = [&](float4 (&sv)[8], int b) {
#pragma unroll
    for (int j = 0; j < 8; j++) {
      bf16x4_t o;
      o.x = (__bf16)sv[j].x; o.y = (__bf16)sv[j].y;
      o.z = (__bf16)sv[j].z; o.w = (__bf16)sv[j].w;
      *(bf16x4_t*)&sA[b][(srow + j * 8) * SAW + scol] = o;
    }
  };

  f32x4 accA[4][2], accB[4][2];
  const f32x4 fzero = {0.f, 0.f, 0.f, 0.f};
  // one wave: cols [wave*32, wave*32+32), 4 M-tiles, 4 k-steps into given acc
  auto gemm = [&](const __bf16* gW, int ldw, int kb, const __bf16* Ab,
                  f32x4 (*acc)[2]) {
#pragma unroll
    for (int ks = 0; ks < 4; ks++) {
      const int kc = kb + ks * 32 + quad * 8;
      bf16x8 b0 = *(const bf16x8*)(gW + (wave * 32 + m) * ldw + kc);
      bf16x8 b1 = *(const bf16x8*)(gW + (wave * 32 + 16 + m) * ldw + kc);
#pragma unroll
      for (int mt = 0; mt < 4; mt++) {
        bf16x8 a = *(const bf16x8*)&Ab[(mt * 16 + m) * SAW + ks * 32 + quad * 8];
        acc[mt][0] = __builtin_amdgcn_mfma_f32_16x16x32_bf16(a, b0, acc[mt][0], 0, 0, 0);
        acc[mt][1] = __builtin_amdgcn_mfma_f32_16x16x32_bf16(a, b1, acc[mt][1], 0, 0, 0);
      }
    }
  };

  // ---- prologue: KE0 + KV0 in flight; mask + Q projection under the latency --
  stage_load(svB, h_KE, HH, 0, 0);
  stage_load(svA, h_KV, HH, 0, 0);
  if (tid < TOKB * KNB)
    sMask[tid / KNB][tid % KNB] = maskp[(long)tok0 * KNB + tid];
  {
    // Q = h_V @ W_Q^T for all 8 tokens: thread (g,o) does 4 independent dots
    const int o = tid & 127, g = tid >> 7;
    const float4* wq = (const float4*)(W_Q + o * HH);
    float qa[4] = {0.f, 0.f, 0.f, 0.f};
#pragma unroll
    for (int j = 0; j < 32; j++) {
      float4 b = wq[j];
#pragma unroll
      for (int t = 0; t < 4; t++) {
        float4 a = *(const float4*)(h_V + (long)(tok0 + g * 4 + t) * HH + j * 4);
        qa[t] += a.x * b.x + a.y * b.y + a.z * b.z + a.w * b.w;
      }
    }
#pragma unroll
    for (int t = 0; t < 4; t++) sQ[g * 4 + t][o] = qa[t];
  }
  stage_store(svB, 0);                 // KE_0 -> buf0
  __syncthreads();

  // ---- steady-state pipeline: per tile 4 phases, loads a full phase ahead ----
  for (int it = 0; it < TILES; ++it) {
    const int tb = 2 * it;
    float lg[4][4];

    // ph1: K1 gemm (buf0=KE); issue EVlo; store KV -> buf1
    stage_load(svB, h_EV, NUMIN, it, 0);
#pragma unroll
    for (int mt = 0; mt < 4; mt++) { accA[mt][0] = fzero; accA[mt][1] = fzero; }
    gemm(bWK1, HH, 0, sA[0], accA);
    stage_store(svA, 1);
    __syncthreads();

    // ph2: K2 gemm (buf1=KV); P=K1*K2; logits+softmax; issue EVhi; store EVlo->buf0
    stage_load(svA, h_EV, NUMIN, it, 128);
#pragma unroll
    for (int mt = 0; mt < 4; mt++) { accB[mt][0] = fzero; accB[mt][1] = fzero; }
    gemm(bWK2, HH, 0, sA[1], accB);
#pragma unroll
    for (int mt = 0; mt < 4; mt++) {
      accA[mt][0] *= accB[mt][0];
      accA[mt][1] *= accB[mt][1];
    }
    {
      float q0[2], q1[2];
#pragma unroll
      for (int nt = 0; nt < 2; nt++) {
        q0[nt] = sQ[tb][wave * 32 + nt * 16 + m];
        q1[nt] = sQ[tb + 1][wave * 32 + nt * 16 + m];
      }
#pragma unroll
      for (int mt = 0; mt < 4; mt++)
#pragma unroll
        for (int r = 0; r < 4; r++) {
          int R = mt * 16 + quad * 4 + r;
          float qa0 = (R < 30) ? q0[0] : q1[0];
          float qa1 = (R < 30) ? q0[1] : q1[1];
          lg[mt][r] = accA[mt][0][r] * qa0 + accA[mt][1][r] * qa1;
        }
#pragma unroll
      for (int d = 1; d < 16; d <<= 1)
#pragma unroll
        for (int mt = 0; mt < 4; mt++)
#pragma unroll
          for (int r = 0; r < 4; r++)
            lg[mt][r] += __shfl_xor(lg[mt][r], d);

      // masked softmax (wave-local, quad-reduce); attend overwrites lg in place
      float mx0 = -3.0e38f, mx1 = -3.0e38f;
#pragma unroll
      for (int mt = 0; mt < 4; mt++)
#pragma unroll
        for (int r = 0; r < 4; r++) {
          int R = mt * 16 + quad * 4 + r;
          if (R < 60) {
            int t = R >= 30, k = R - 30 * t;
            float l = (sMask[tb + t][k] > 0.f) ? lg[mt][r] * 0.03125f : -3.0e38f;
            lg[mt][r] = l;
            if (t == 0) mx0 = fmaxf(mx0, l); else mx1 = fmaxf(mx1, l);
          } else lg[mt][r] = -3.0e38f;
        }
      mx0 = fmaxf(mx0, __shfl_xor(mx0, 16)); mx0 = fmaxf(mx0, __shfl_xor(mx0, 32));
      mx1 = fmaxf(mx1, __shfl_xor(mx1, 16)); mx1 = fmaxf(mx1, __shfl_xor(mx1, 32));
      float s0 = 0.f, s1 = 0.f;
#pragma unroll
      for (int mt = 0; mt < 4; mt++)
#pragma unroll
        for (int r = 0; r < 4; r++) {
          int R = mt * 16 + quad * 4 + r;
          float e = 0.f;
          if (R < 60) {
            int t = R >= 30, k = R - 30 * t;
            if (sMask[tb + t][k] > 0.f) {
              float mxt = (t == 0) ? mx0 : mx1;
              e = __expf(lg[mt][r] - mxt);
            }
            if (t == 0) s0 += e; else s1 += e;
          }
          lg[mt][r] = e;
        }
      s0 += __shfl_xor(s0, 16); s0 += __shfl_xor(s0, 32);
      s1 += __shfl_xor(s1, 16); s1 += __shfl_xor(s1, 32);
      float inv0 = (s0 > 0.f) ? 1.f / s0 : 0.f;
      float inv1 = (s1 > 0.f) ? 1.f / s1 : 0.f;
#pragma unroll
      for (int mt = 0; mt < 4; mt++)
#pragma unroll
        for (int r = 0; r < 4; r++) {
          int R = mt * 16 + quad * 4 + r;
          lg[mt][r] *= (R < 30) ? inv0 : inv1;
        }
    }
    stage_store(svB, 0);               // EVlo -> buf0
    __syncthreads();

    // ph3: V gemm lo (buf0=EVlo); issue next-tile KE; store EVhi -> buf1
    if (it + 1 < TILES) stage_load(svB, h_KE, HH, it + 1, 0);
#pragma unroll
    for (int mt = 0; mt < 4; mt++) { accB[mt][0] = fzero; accB[mt][1] = fzero; }
    gemm(bWV, NUMIN, 0, sA[0], accB);
    stage_store(svA, 1);               // EVhi -> buf1
    __syncthreads();

    // ph4: V gemm hi (buf1, accumulate); agg -> sU; issue next KV; store KE->buf0
    if (it + 1 < TILES) stage_load(svA, h_KV, HH, it + 1, 0);
    gemm(bWV, NUMIN, 128, sA[1], accB);
    {
      float u00 = 0.f, u01 = 0.f, u10 = 0.f, u11 = 0.f;
#pragma unroll
      for (int mt = 0; mt < 4; mt++)
#pragma unroll
        for (int r = 0; r < 4; r++) {
          int R = mt * 16 + quad * 4 + r;
          if (R < 30) {
            u00 += lg[mt][r] * accB[mt][0][r];
            u01 += lg[mt][r] * accB[mt][1][r];
          } else if (R < 60) {
            u10 += lg[mt][r] * accB[mt][0][r];
            u11 += lg[mt][r] * accB[mt][1][r];
          }
        }
      u00 += __shfl_xor(u00, 16); u00 += __shfl_xor(u00, 32);
      u01 += __shfl_xor(u01, 16); u01 += __shfl_xor(u01, 32);
      u10 += __shfl_xor(u10, 16); u10 += __shfl_xor(u10, 32);
      u11 += __shfl_xor(u11, 16); u11 += __shfl_xor(u11, 32);
      if (quad == 0) {
        sU[tb][wave * 32 + m]          = u00;
        sU[tb][wave * 32 + 16 + m]     = u01;
        sU[tb + 1][wave * 32 + m]      = u10;
        sU[tb + 1][wave * 32 + 16 + m] = u11;
      }
    }
    if (it + 1 < TILES) stage_store(svB, 0);   // KE_{it+1} -> buf0
    __syncthreads();
  }

  // ---- epilogue: out = h_upd @ W_O^T for all 8 tokens, 4-way ILP ----
  {
    const int o = tid & 127, g = tid >> 7;
    const float4* wo = (const float4*)(W_O + o * HH);
    float r[4] = {0.f, 0.f, 0.f, 0.f};
#pragma unroll
    for (int j = 0; j < 32; j++) {
      float4 b = wo[j];
#pragma unroll
      for (int t = 0; t < 4; t++) {
        float4 a = *(const float4*)(&sU[g * 4 + t][j * 4]);
        r[t] += a.x * b.x + a.y * b.y + a.z * b.z + a.w * b.w;
      }
    }
#pragma unroll
    for (int t = 0; t < 4; t++)
      out[(long)(tok0 + g * 4 + t) * HH + o] = r[t];
  }
}

extern "C" void kernel_launch(void* const* d_in, const int* in_sizes, int n_in,
                              void* d_out, int out_size, void* d_ws, size_t ws_size,
                              hipStream_t stream) {
  const float* h_V  = (const float*)d_in[0];
  const float* h_EV = (const float*)d_in[1];
  const float* h_KV = (const float*)d_in[2];
  const float* h_KE = (const float*)d_in[3];
  const float* mask = (const float*)d_in[4];
  const float* W_Q  = (const float*)d_in[5];
  const float* W_K1 = (const float*)d_in[6];
  const float* W_K2 = (const float*)d_in[7];
  const float* W_V  = (const float*)d_in[8];
  const float* W_O  = (const float*)d_in[9];
  __bf16* bW = (__bf16*)d_ws;

  conv_w_kernel<<<64, 256, 0, stream>>>(W_K1, W_K2, W_V, bW);
  na_main_kernel<<<NBLK, 256, 0, stream>>>(h_V, h_EV, h_KV, h_KE, mask,
                                           W_Q, W_O, bW, (float*)d_out);
}